// Round 6
// baseline (2592.007 us; speedup 1.0000x reference)
//
#include <hip/hip_runtime.h>
#include <cstdint>
#include <cstddef>

#define B_  2
#define C_  256
#define NH_ 8
#define LV_ 4
#define P_  4
#define L_  6
#define F_  1024
#define N_  21760
#define M_  (B_*N_)   // 43520

typedef unsigned short ushort_t;
typedef __attribute__((ext_vector_type(8))) short bf16x8;
typedef __attribute__((ext_vector_type(4))) float f32x4;

__device__ __forceinline__ float b2f(ushort_t u){
    union { unsigned int i; float f; } v; v.i = ((unsigned int)u) << 16; return v.f;
}
__device__ __forceinline__ ushort_t f2b(float f){
    union { float f; unsigned int i; } v; v.f = f;
    return (ushort_t)((v.i + 0x7fffu + ((v.i >> 16) & 1u)) >> 16);
}
__device__ __forceinline__ float lof(int u){ return __int_as_float(u << 16); }
__device__ __forceinline__ float hif(int u){ return __int_as_float(u & 0xffff0000); }

// async global->LDS, 16B per lane, dst = wave-uniform base + lane*16
__device__ __forceinline__ void gload16(const void* g, void* l){
    __builtin_amdgcn_global_load_lds(
        (const __attribute__((address_space(1))) unsigned int*)g,
        (__attribute__((address_space(3))) unsigned int*)l, 16, 0, 0);
}

// ---------------------------------------------------------------------------
// Coalesced concat+transpose init (32x32 LDS tiles).
// ---------------------------------------------------------------------------
__global__ __launch_bounds__(256) void concat_init_kernel(
    const float* __restrict__ s0, const float* __restrict__ s1,
    const float* __restrict__ s2, const float* __restrict__ s3,
    const float* __restrict__ p0, const float* __restrict__ p1,
    const float* __restrict__ p2, const float* __restrict__ p3,
    const float* __restrict__ le, float* __restrict__ X,
    ushort_t* __restrict__ POSB, ushort_t* __restrict__ XB,
    ushort_t* __restrict__ QB)
{
    int bid = blockIdx.x;
    int b = bid / 5440;
    int r = bid - b * 5440;
    const float* sp; const float* pp; int li, st, hw, t;
    if      (r < 4096){ li=0; st=0;     hw=16384; t=r;        sp=s0; pp=p0; }
    else if (r < 5120){ li=1; st=16384; hw=4096;  t=r-4096;   sp=s1; pp=p1; }
    else if (r < 5376){ li=2; st=20480; hw=1024;  t=r-5120;   sp=s2; pp=p2; }
    else              { li=3; st=21504; hw=256;   t=r-5376;   sp=s3; pp=p3; }
    int pt = t >> 3, ct = t & 7;

    __shared__ float ts[32][33], tp[32][33];
    int tx  = threadIdx.x & 31;
    int ty8 = threadIdx.x >> 5;
#pragma unroll
    for (int i = 0; i < 4; i++) {
        int c   = ct * 32 + ty8 + i * 8;
        int pix = pt * 32 + tx;
        size_t so = ((size_t)b * C_ + c) * hw + pix;
        ts[ty8 + i * 8][tx] = sp[so];
        tp[ty8 + i * 8][tx] = pp[so];
    }
    __syncthreads();
#pragma unroll
    for (int i = 0; i < 4; i++) {
        int cw = tx, pw = ty8 + i * 8;
        int c = ct * 32 + cw;
        int n = st + pt * 32 + pw;
        size_t o = ((size_t)b * N_ + n) * C_ + c;
        float xv = ts[cw][pw];
        float pv = tp[cw][pw] + le[li * C_ + c];
        X[o]    = xv;
        XB[o]   = f2b(xv);
        POSB[o] = f2b(pv);
        QB[o]   = f2b(xv + pv);
    }
}

// ---------------------------------------------------------------------------
// Weight prep, coalesced: fp32 [L][K][N] -> bf16 [l][n][k] via 32x33 LDS tile.
// ---------------------------------------------------------------------------
__global__ __launch_bounds__(256) void wprep_t_kernel(
    const float* __restrict__ in, ushort_t* __restrict__ out,
    int K, int Nn, long outLayerStride)
{
    int tk = K >> 5, tn = Nn >> 5, per = tk * tn;
    int bid = blockIdx.x;
    int l  = bid / per;
    int r  = bid - l * per;
    int kt = r / tn, nt = r - kt * tn;

    __shared__ float t[32][33];
    int tx = threadIdx.x & 31, ty8 = threadIdx.x >> 5;
#pragma unroll
    for (int i = 0; i < 4; i++) {
        int k = kt * 32 + ty8 + i * 8;
        int n = nt * 32 + tx;
        t[ty8 + i * 8][tx] = in[((long)l * K + k) * Nn + n];
    }
    __syncthreads();
#pragma unroll
    for (int i = 0; i < 4; i++) {
        int k = kt * 32 + tx;
        int n = nt * 32 + ty8 + i * 8;
        out[(long)l * outLayerStride + (long)n * K + k] = f2b(t[tx][ty8 + i * 8]);
    }
}

// packed bias for fused off+att GEMM: pb[l][0:256]=boff, [256:384]=batt
__global__ __launch_bounds__(256) void bias_pack_kernel(
    const float* __restrict__ boff, const float* __restrict__ batt,
    float* __restrict__ pb)
{
    int i = blockIdx.x * 256 + threadIdx.x;
    if (i >= 6 * 384) return;
    int l = i / 384, j = i - l * 384;
    pb[i] = (j < 256) ? boff[l * 256 + j] : batt[l * 128 + j - 256];
}

// ---------------------------------------------------------------------------
// bf16 MFMA GEMM (unfused): 128x128 tile, BK=64 two-half staging.
// Output: bf16 Cb, or fp32 split (Cf/Cf2 at Nsplit).
// ---------------------------------------------------------------------------
__global__ __launch_bounds__(256) void gemm_bf16_kernel(
    const ushort_t* __restrict__ A, const ushort_t* __restrict__ BT,
    const float* __restrict__ bias,
    ushort_t* __restrict__ Cb, float* __restrict__ Cf, float* __restrict__ Cf2,
    int M, int Nn, int K, int Nsplit, int relu)
{
    __shared__ ushort_t Alds[2][128*32];
    __shared__ ushort_t Blds[2][128*32];
    const int tid  = threadIdx.x;
    const int wave = tid >> 6, lane = tid & 63;
    const int bm = blockIdx.y * 128, bn = blockIdx.x * 128;
    const int wm = (wave >> 1) * 64, wn = (wave & 1) * 64;

    const int c0 = wave * 2, c1 = wave * 2 + 1;
    const int rIn = lane >> 2;
    const int cIn = (lane & 3) * 8;
    const ushort_t* Ag0 = A  + (size_t)(bm + c0*16 + rIn) * K + cIn;
    const ushort_t* Ag1 = A  + (size_t)(bm + c1*16 + rIn) * K + cIn;
    const ushort_t* Bg0 = BT + (size_t)(bn + c0*16 + rIn) * K + cIn;
    const ushort_t* Bg1 = BT + (size_t)(bn + c1*16 + rIn) * K + cIn;

    const int fm    = lane & 15;
    const int quad8 = (lane >> 4) * 8;

    f32x4 acc[4][4];
#pragma unroll
    for (int i = 0; i < 4; i++)
#pragma unroll
        for (int j = 0; j < 4; j++) acc[i][j] = (f32x4){0.f,0.f,0.f,0.f};

    for (int k0 = 0; k0 < K; k0 += 64) {
        gload16(Ag0 + k0,      &Alds[0][c0*512]);
        gload16(Ag1 + k0,      &Alds[0][c1*512]);
        gload16(Bg0 + k0,      &Blds[0][c0*512]);
        gload16(Bg1 + k0,      &Blds[0][c1*512]);
        gload16(Ag0 + k0 + 32, &Alds[1][c0*512]);
        gload16(Ag1 + k0 + 32, &Alds[1][c1*512]);
        gload16(Bg0 + k0 + 32, &Blds[1][c0*512]);
        gload16(Bg1 + k0 + 32, &Blds[1][c1*512]);
        __syncthreads();
#pragma unroll
        for (int h = 0; h < 2; h++) {
            bf16x8 af[4], bfr[4];
#pragma unroll
            for (int i = 0; i < 4; i++)
                af[i]  = *(const bf16x8*)&Alds[h][(wm + i*16 + fm) * 32 + quad8];
#pragma unroll
            for (int j = 0; j < 4; j++)
                bfr[j] = *(const bf16x8*)&Blds[h][(wn + j*16 + fm) * 32 + quad8];
#pragma unroll
            for (int i = 0; i < 4; i++)
#pragma unroll
                for (int j = 0; j < 4; j++)
                    acc[i][j] = __builtin_amdgcn_mfma_f32_16x16x32_bf16(af[i], bfr[j], acc[i][j], 0, 0, 0);
        }
        __syncthreads();
    }

    const int rq = (lane >> 4) * 4;
#pragma unroll
    for (int j = 0; j < 4; j++) {
        int col = bn + wn + j*16 + fm;
        float bb = bias[col];
#pragma unroll
        for (int i = 0; i < 4; i++) {
            int row0 = bm + wm + i*16 + rq;
#pragma unroll
            for (int r = 0; r < 4; r++) {
                float v = acc[i][j][r] + bb;
                if (relu) v = fmaxf(v, 0.f);
                if (Cb) {
                    Cb[(size_t)(row0 + r) * Nn + col] = f2b(v);
                } else if (col < Nsplit) {
                    Cf[(size_t)(row0 + r) * Nsplit + col] = v;
                } else {
                    Cf2[(size_t)(row0 + r) * (Nn - Nsplit) + (col - Nsplit)] = v;
                }
            }
        }
    }
}

// ---------------------------------------------------------------------------
// Fused GEMM + residual + LayerNorm. N fixed = 256 (full row per block).
// C = A @ BT^T + bias;  x = LN(x + C)*g + beta;  writes X fp32, XB bf16,
// optional QB = bf16(x + POSB). Tile 128 rows x 256 cols, 4 waves 2x2.
// ---------------------------------------------------------------------------
__global__ __launch_bounds__(256) void gemm_ln_kernel(
    const ushort_t* __restrict__ A, const ushort_t* __restrict__ BT,
    const float* __restrict__ bias,
    float* __restrict__ X, const float* __restrict__ g,
    const float* __restrict__ beta, ushort_t* __restrict__ XB,
    const ushort_t* __restrict__ POSB, ushort_t* __restrict__ QB, int K)
{
    __shared__ ushort_t Alds[2][128*32];
    __shared__ ushort_t Blds[2][256*32];
    const int tid  = threadIdx.x;
    const int wave = tid >> 6, lane = tid & 63;
    const int bm = blockIdx.y * 128;
    const int wr = wave >> 1, wc = wave & 1;   // row-half, col-half

    const int c0 = wave * 2, c1 = wave * 2 + 1;
    const int rIn = lane >> 2;
    const int cIn = (lane & 3) * 8;
    const ushort_t* Ag0 = A + (size_t)(bm + c0*16 + rIn) * K + cIn;
    const ushort_t* Ag1 = A + (size_t)(bm + c1*16 + rIn) * K + cIn;
    const ushort_t* Bg[4];
#pragma unroll
    for (int q = 0; q < 4; q++)
        Bg[q] = BT + (size_t)((wave*4 + q)*16 + rIn) * K + cIn;

    const int fm    = lane & 15;
    const int quad8 = (lane >> 4) * 8;
    const int rq    = (lane >> 4) * 4;

    f32x4 acc[4][8];
#pragma unroll
    for (int i = 0; i < 4; i++)
#pragma unroll
        for (int j = 0; j < 8; j++) acc[i][j] = (f32x4){0.f,0.f,0.f,0.f};

    for (int k0 = 0; k0 < K; k0 += 64) {
        gload16(Ag0 + k0,      &Alds[0][c0*512]);
        gload16(Ag1 + k0,      &Alds[0][c1*512]);
        gload16(Ag0 + k0 + 32, &Alds[1][c0*512]);
        gload16(Ag1 + k0 + 32, &Alds[1][c1*512]);
#pragma unroll
        for (int q = 0; q < 4; q++) {
            gload16(Bg[q] + k0,      &Blds[0][(wave*4+q)*512]);
            gload16(Bg[q] + k0 + 32, &Blds[1][(wave*4+q)*512]);
        }
        __syncthreads();
#pragma unroll
        for (int h = 0; h < 2; h++) {
            bf16x8 af[4], bfr[8];
#pragma unroll
            for (int i = 0; i < 4; i++)
                af[i]  = *(const bf16x8*)&Alds[h][(wr*64 + i*16 + fm) * 32 + quad8];
#pragma unroll
            for (int j = 0; j < 8; j++)
                bfr[j] = *(const bf16x8*)&Blds[h][(wc*128 + j*16 + fm) * 32 + quad8];
#pragma unroll
            for (int i = 0; i < 4; i++)
#pragma unroll
                for (int j = 0; j < 8; j++)
                    acc[i][j] = __builtin_amdgcn_mfma_f32_16x16x32_bf16(af[i], bfr[j], acc[i][j], 0, 0, 0);
        }
        __syncthreads();
    }

    // ---- epilogue: residual + stats ----
    float* S = (float*)&Alds[0][0];       // 256 rows x {sum, sumsq}
    float ps[4][4], ps2[4][4];
#pragma unroll
    for (int i = 0; i < 4; i++)
#pragma unroll
        for (int r = 0; r < 4; r++) { ps[i][r] = 0.f; ps2[i][r] = 0.f; }

    int colj[8]; float bb[8];
#pragma unroll
    for (int j = 0; j < 8; j++) { colj[j] = wc*128 + j*16 + fm; bb[j] = bias[colj[j]]; }

#pragma unroll
    for (int i = 0; i < 4; i++)
#pragma unroll
        for (int r = 0; r < 4; r++) {
            int row = bm + wr*64 + i*16 + rq + r;
#pragma unroll
            for (int j = 0; j < 8; j++) {
                float t = acc[i][j][r] + bb[j] + X[(size_t)row * 256 + colj[j]];
                acc[i][j][r] = t;
                ps[i][r]  += t;
                ps2[i][r] += t * t;
            }
        }
#pragma unroll
    for (int m = 1; m < 16; m <<= 1)
#pragma unroll
        for (int i = 0; i < 4; i++)
#pragma unroll
            for (int r = 0; r < 4; r++) {
                ps[i][r]  += __shfl_xor(ps[i][r],  m, 64);
                ps2[i][r] += __shfl_xor(ps2[i][r], m, 64);
            }
    if (fm == 0) {
#pragma unroll
        for (int i = 0; i < 4; i++)
#pragma unroll
            for (int r = 0; r < 4; r++) {
                int idx = (wr*2 + wc)*64 + i*16 + rq + r;
                S[idx*2]   = ps[i][r];
                S[idx*2+1] = ps2[i][r];
            }
    }
    __syncthreads();

    float mu_[4][4], rs_[4][4];
#pragma unroll
    for (int i = 0; i < 4; i++)
#pragma unroll
        for (int r = 0; r < 4; r++) {
            int i0 = wr*128 + i*16 + rq + r;
            float s  = S[i0*2]   + S[(i0+64)*2];
            float s2 = S[i0*2+1] + S[(i0+64)*2+1];
            float mu  = s * (1.f/256.f);
            float var = s2 * (1.f/256.f) - mu*mu;
            mu_[i][r] = mu;
            rs_[i][r] = rsqrtf(var + 1e-5f);
        }

    float gj[8], bej[8];
#pragma unroll
    for (int j = 0; j < 8; j++) { gj[j] = g[colj[j]]; bej[j] = beta[colj[j]]; }

#pragma unroll
    for (int i = 0; i < 4; i++)
#pragma unroll
        for (int r = 0; r < 4; r++) {
            int row = bm + wr*64 + i*16 + rq + r;
#pragma unroll
            for (int j = 0; j < 8; j++) {
                size_t o = (size_t)row * 256 + colj[j];
                float v = (acc[i][j][r] - mu_[i][r]) * rs_[i][r] * gj[j] + bej[j];
                X[o]  = v;
                XB[o] = f2b(v);
                if (QB) QB[o] = f2b(v + b2f(POSB[o]));
            }
        }
}

// ---------------------------------------------------------------------------
// Deformable sampling, conflict-free swizzled LDS + 16B gathers.
// Block = 128 thr per query.
// Phase 1: thread = (head, li, p): softmax; fold attn*bilinear*valid into
//          (byte-offset, weight) int2; store swizzled:
//          s = (head>>2)*256 + (j&15)*16 + (head&3)*4 + (j>>4), j = pt*4+corner.
// Phase 2: thread = (head, jg, dg): 16 iters, dwordx4 gather (8 dims),
//          xor-reduce over jg.
// ---------------------------------------------------------------------------
__global__ __launch_bounds__(128) void msdeform_kernel(
    const ushort_t* __restrict__ VALb, const float* __restrict__ OFF,
    const float* __restrict__ ATT, ushort_t* __restrict__ SAMPb)
{
    const int bn = blockIdx.x;
    const int b = bn / N_;
    const int n = bn - b * N_;
    const int tid = threadIdx.x;
    const int head = tid >> 4, t15 = tid & 15;
    const int wv = head >> 2, hw4 = (head & 3) * 4;

    __shared__ int2 s_wi[512];

    {   // phase 1
        const int li = (tid >> 2) & 3;
        float logit = ATT[(size_t)bn * 128 + tid];
        float ox = OFF[(size_t)bn * 256 + tid * 2 + 0];
        float oy = OFF[(size_t)bn * 256 + tid * 2 + 1];
        float mx = logit;
#pragma unroll
        for (int s = 1; s < 16; s <<= 1) mx = fmaxf(mx, __shfl_xor(mx, s, 16));
        float e = __expf(logit - mx), sm = e;
#pragma unroll
        for (int s = 1; s < 16; s <<= 1) sm += __shfl_xor(sm, s, 16);
        float aw = e / sm;

        int sq, lwq;
        if      (n < 16384){ sq = 0;     lwq = 7; }
        else if (n < 20480){ sq = 16384; lwq = 6; }
        else if (n < 21504){ sq = 20480; lwq = 5; }
        else               { sq = 21504; lwq = 4; }
        int pidx = n - sq;
        int prow = pidx >> lwq, pcol = pidx & ((1 << lwq) - 1);
        float inv = 1.f / (float)(1 << lwq);
        float refx = (pcol + 0.5f) * inv;
        float refy = (prow + 0.5f) * inv;

        const int HS[4] = {128, 64, 32, 16};
        const int ST[4] = {0, 16384, 20480, 21504};
        int wl = HS[li], st = ST[li];
        float fw = (float)wl;
        float xx = refx * fw + ox - 0.5f;
        float yy = refy * fw + oy - 0.5f;
        float xf = floorf(xx), yf = floorf(yy);
        float wx = xx - xf, wy = yy - yf;
        int x0 = (int)xf, y0 = (int)yf;
        const int jgw = t15 >> 2;           // j>>4 for this thread's 4 j's
#pragma unroll
        for (int c2 = 0; c2 < 4; c2++) {
            int dx = c2 & 1, dy = c2 >> 1;
            int xi = x0 + dx, yi = y0 + dy;
            float wgt = (dx ? wx : 1.f - wx) * (dy ? wy : 1.f - wy);
            bool valid = (xi >= 0) & (xi < wl) & (yi >= 0) & (yi < wl);
            int xc = min(max(xi, 0), wl - 1), yc = min(max(yi, 0), wl - 1);
            int i15 = (t15 & 3) * 4 + c2;   // j & 15
            int2 wi;
            wi.x = ((st + yc * wl + xc) * C_ + head * 32) * 2;   // byte offset
            wi.y = __float_as_int(valid ? aw * wgt : 0.f);
            s_wi[wv*256 + i15*16 + hw4 + jgw] = wi;
        }
    }
    __syncthreads();

    // phase 2
    const int jg = (tid >> 2) & 3, dg = tid & 3;
    const char* vb = (const char*)VALb + (size_t)b * N_ * C_ * 2 + dg * 16;
    const int sbase = wv*256 + hw4 + jg;
    float a[8];
#pragma unroll
    for (int e = 0; e < 8; e++) a[e] = 0.f;
#pragma unroll
    for (int i2 = 0; i2 < 16; i2++) {
        int2 wi = s_wi[sbase + i2*16];
        float w = __int_as_float(wi.y);
        int4 u = *(const int4*)(vb + wi.x);
        a[0] += w * lof(u.x); a[1] += w * hif(u.x);
        a[2] += w * lof(u.y); a[3] += w * hif(u.y);
        a[4] += w * lof(u.z); a[5] += w * hif(u.z);
        a[6] += w * lof(u.w); a[7] += w * hif(u.w);
    }
#pragma unroll
    for (int e = 0; e < 8; e++) {
        a[e] += __shfl_xor(a[e], 4, 64);
        a[e] += __shfl_xor(a[e], 8, 64);
    }
    if (jg == 0) {
        uint4 o;
        o.x = (uint)f2b(a[0]) | ((uint)f2b(a[1]) << 16);
        o.y = (uint)f2b(a[2]) | ((uint)f2b(a[3]) << 16);
        o.z = (uint)f2b(a[4]) | ((uint)f2b(a[5]) << 16);
        o.w = (uint)f2b(a[6]) | ((uint)f2b(a[7]) << 16);
        *(uint4*)(SAMPb + (size_t)bn * C_ + head * 32 + dg * 8) = o;
    }
}

// ---------------------------------------------------------------------------
// Workspace: POSB | OFFf | ATTf | SAMPB | VALB | XB | QB | WT | PB (~185 MB)
//   FFN hidden HB (bf16, M*1024) overlays [OFFf|ATTf|SAMPB] exactly.
// ---------------------------------------------------------------------------
extern "C" void kernel_launch(void* const* d_in, const int* in_sizes, int n_in,
                              void* d_out, int out_size, void* d_ws, size_t ws_size,
                              hipStream_t stream)
{
    const float *srcs[4], *poss[4];
    if (in_sizes[1] == in_sizes[0]) {   // interleaved src0,pos0,src1,pos1,...
        srcs[0] = (const float*)d_in[0]; poss[0] = (const float*)d_in[1];
        srcs[1] = (const float*)d_in[2]; poss[1] = (const float*)d_in[3];
        srcs[2] = (const float*)d_in[4]; poss[2] = (const float*)d_in[5];
        srcs[3] = (const float*)d_in[6]; poss[3] = (const float*)d_in[7];
    } else {
        srcs[0] = (const float*)d_in[0]; srcs[1] = (const float*)d_in[1];
        srcs[2] = (const float*)d_in[2]; srcs[3] = (const float*)d_in[3];
        poss[0] = (const float*)d_in[4]; poss[1] = (const float*)d_in[5];
        poss[2] = (const float*)d_in[6]; poss[3] = (const float*)d_in[7];
    }
    const float* le = (const float*)d_in[8];

    float* X = (float*)d_out;
    char* w = (char*)d_ws;
    ushort_t* POSB  = (ushort_t*)w;           w += (size_t)M_ * C_ * 2;
    float*    OFFf  = (float*)w;              w += (size_t)M_ * C_ * 4;
    float*    ATTf  = (float*)w;              w += (size_t)M_ * 128 * 4;
    ushort_t* SAMPB = (ushort_t*)w;           w += (size_t)M_ * C_ * 2;
    ushort_t* VALB  = (ushort_t*)w;           w += (size_t)M_ * C_ * 2;
    ushort_t* XB    = (ushort_t*)w;           w += (size_t)M_ * C_ * 2;
    ushort_t* QB    = (ushort_t*)w;           w += (size_t)M_ * C_ * 2;
    ushort_t* WT    = (ushort_t*)w;           w += (size_t)6 * 753664 * 2;
    float*    PB    = (float*)w;
    ushort_t* HB    = (ushort_t*)OFFf;        // overlays OFFf|ATTf|SAMPB exactly

    const long LSTRIDE = 753664;
    const long O_WVAL = 0, O_WOFF = 65536, O_WATT = 131072, O_WOUT = 163840,
               O_WF1 = 229376, O_WF2 = 491520;

    wprep_t_kernel<<<6*8*8,   256, 0, stream>>>((const float*)d_in[13], WT + O_WVAL, 256, 256,  LSTRIDE);
    wprep_t_kernel<<<6*8*8,   256, 0, stream>>>((const float*)d_in[9],  WT + O_WOFF, 256, 256,  LSTRIDE);
    wprep_t_kernel<<<6*8*4,   256, 0, stream>>>((const float*)d_in[11], WT + O_WATT, 256, 128,  LSTRIDE);
    wprep_t_kernel<<<6*8*8,   256, 0, stream>>>((const float*)d_in[15], WT + O_WOUT, 256, 256,  LSTRIDE);
    wprep_t_kernel<<<6*8*32,  256, 0, stream>>>((const float*)d_in[19], WT + O_WF1,  256, 1024, LSTRIDE);
    wprep_t_kernel<<<6*32*8,  256, 0, stream>>>((const float*)d_in[21], WT + O_WF2,  1024, 256, LSTRIDE);
    bias_pack_kernel<<<9, 256, 0, stream>>>((const float*)d_in[10], (const float*)d_in[12], PB);

    concat_init_kernel<<<2*5440, 256, 0, stream>>>(srcs[0], srcs[1], srcs[2], srcs[3],
                                                   poss[0], poss[1], poss[2], poss[3],
                                                   le, X, POSB, XB, QB);

    for (int l = 0; l < L_; l++) {
        const ushort_t* wt = WT + (size_t)l * LSTRIDE;
        const float* bval = (const float*)d_in[14] + (size_t)l * C_;
        const float* bout = (const float*)d_in[16] + (size_t)l * C_;
        const float* g1   = (const float*)d_in[17] + (size_t)l * C_;
        const float* b1   = (const float*)d_in[18] + (size_t)l * C_;
        const float* bf1  = (const float*)d_in[20] + (size_t)l * F_;
        const float* bf2  = (const float*)d_in[22] + (size_t)l * C_;
        const float* g2   = (const float*)d_in[23] + (size_t)l * C_;
        const float* b2   = (const float*)d_in[24] + (size_t)l * C_;

        gemm_bf16_kernel<<<dim3(2, M_/128), 256, 0, stream>>>(XB, wt + O_WVAL, bval,
            VALB, nullptr, nullptr, M_, 256, 256, 256, 0);
        gemm_bf16_kernel<<<dim3(3, M_/128), 256, 0, stream>>>(QB, wt + O_WOFF, PB + (size_t)l*384,
            nullptr, OFFf, ATTf, M_, 384, 256, 256, 0);
        msdeform_kernel<<<M_, 128, 0, stream>>>(VALB, OFFf, ATTf, SAMPB);
        gemm_ln_kernel<<<dim3(1, M_/128), 256, 0, stream>>>(SAMPB, wt + O_WOUT, bout,
            X, g1, b1, XB, nullptr, nullptr, 256);
        gemm_bf16_kernel<<<dim3(8, M_/128), 256, 0, stream>>>(XB, wt + O_WF1, bf1,
            HB, nullptr, nullptr, M_, 1024, 256, 1024, 1);
        gemm_ln_kernel<<<dim3(1, M_/128), 256, 0, stream>>>(HB, wt + O_WF2, bf2,
            X, g2, b2, XB, POSB, QB, 1024);
    }
}